// Round 5
// baseline (17.799 us; speedup 1.0000x reference)
//
#include <hip/hip_runtime.h>
#include <math.h>

typedef float f32x4 __attribute__((ext_vector_type(4)));   // native vector: OK for nontemporal builtins

__device__ __forceinline__ float frcp(float x) { return __builtin_amdgcn_rcpf(x); }

// Per-element SPU linear-bound computation, branchless, transcendental-minimized.
// For x < 0:  spu(x) = 1/(1+e^x) - 1,  spu_grad(x) = -e^x/(1+e^x)^2  (== -0.5/(cosh x + 1))
// For x >= 0: spu(x) = x^2 - 0.5,      spu_grad(x) = 2x
__device__ __forceinline__ void spu_bounds(float l, float u, float& nl, float& nu) {
    const float mid = 0.5f * (l + u);

    // one exp per point; shared between value and gradient
    const float e_l = __expf(l);
    const float e_u = __expf(u);
    const float e_m = __expf(mid);
    const float r_l = frcp(1.0f + e_l);
    const float r_u = frcp(1.0f + e_u);
    const float r_m = frcp(1.0f + e_m);

    const float sl = (l   >= 0.0f) ? fmaf(l,   l,   -0.5f) : (r_l - 1.0f);
    const float su = (u   >= 0.0f) ? fmaf(u,   u,   -0.5f) : (r_u - 1.0f);
    const float sm = (mid >= 0.0f) ? fmaf(mid, mid, -0.5f) : (r_m - 1.0f);
    const float gm = (mid >= 0.0f) ? (2.0f * mid)
                   : ((mid <= -50.0f) ? 0.0f : (-e_m * r_m * r_m));

    // chord between (l, sl) and (u, su)
    const float a_lu = (su - sl) * frcp(u - l + 1e-8f);
    const float b_lu = sl - l * a_lu;

    // tangent at midpoint (only consumed when neg or pos)
    const float a_t = gm;
    const float b_t = sm - gm * mid;

    const bool neg    = (u < 0.0f);
    const bool pos    = (!neg) && (l > 0.0f);
    const bool mixed  = (!neg) && (!pos);
    const bool normal = mixed && (su > sl);

    // mixed lower-bound candidates (only consumed when mixed, where l<=0, u>=0)
    // c1: chord from (l, sl) to (0, -0.5)
    const float a1 = (-0.5f - sl) * frcp(1e-8f - l);
    const float b1 = sl - l * a1;
    // c2: tangent at h=u/2 >= 0  ->  a2 = 2h = u,  b2 = (h^2-0.5) - a2*h = -u^2/4 - 0.5
    const float a2 = u;
    const float b2 = -fmaf(0.25f * u, u, 0.5f);

    // area proxy: area(a,b) = -(u-l)*(a*(l+u) + 2b)
    const float dlu = u - l;
    const float slu = u + l;
    const float ar0 = dlu;                                   // a=0, b=-0.5
    const float ar1 = -dlu * fmaf(a1, slu, 2.0f * b1);
    const float ar2 = normal ? (-dlu * fmaf(a2, slu, 2.0f * b2)) : INFINITY;

    // argmin over [ar0, ar1, ar2], first-min on ties (jnp.argmin semantics)
    int idx = 0;
    float best = ar0;
    if (ar1 < best) { best = ar1; idx = 1; }
    if (ar2 < best) { idx = 2; }
    const float a_m = (idx == 0) ? 0.0f  : ((idx == 1) ? a1 : a2);
    const float b_m = (idx == 0) ? -0.5f : ((idx == 1) ? b1 : b2);

    const float lw = neg ? a_lu : (pos ? a_t : a_m);
    const float lb = neg ? b_lu : (pos ? b_t : b_m);
    const float uw = neg ? a_t : ((pos || normal) ? a_lu : 0.0f);
    const float ub = neg ? b_t : ((pos || normal) ? b_lu : sl);

    nl = lb + ((lw > 0.0f) ? lw * l : lw * u);
    nu = ub + ((uw > 0.0f) ? uw * u : uw * l);
}

__device__ __forceinline__ void spu_bounds4(const f32x4 lv, const f32x4 uv,
                                            f32x4& a, f32x4& b) {
    float a0, b0, a1, b1, a2, b2, a3, b3;
    spu_bounds(lv.x, uv.x, a0, b0);
    spu_bounds(lv.y, uv.y, a1, b1);
    spu_bounds(lv.z, uv.z, a2, b2);
    spu_bounds(lv.w, uv.w, a3, b3);
    a.x = a0; a.y = a1; a.z = a2; a.w = a3;
    b.x = b0; b.y = b1; b.z = b2; b.w = b3;
}

__global__ void __launch_bounds__(256) spu_pointwise_kernel(
        const float* __restrict__ l, const float* __restrict__ u,
        float* __restrict__ out_nl, float* __restrict__ out_nu,
        int n4, int n) {
    const int tid = blockIdx.x * blockDim.x + threadIdx.x;
    const int stride = gridDim.x * blockDim.x;
    const int pairs = n4 >> 1;

    const f32x4* __restrict__ l4 = reinterpret_cast<const f32x4*>(l);
    const f32x4* __restrict__ u4 = reinterpret_cast<const f32x4*>(u);
    f32x4* __restrict__ nl4 = reinterpret_cast<f32x4*>(out_nl);
    f32x4* __restrict__ nu4 = reinterpret_cast<f32x4*>(out_nu);

    // 2 independent float4s per thread: all 4 loads issued before compute,
    // two interleavable ALU chains, then 4 stores. Pure streaming -> nontemporal.
    for (int i = tid; i < pairs; i += stride) {
        const int j = i + pairs;
        const f32x4 lv0 = __builtin_nontemporal_load(l4 + i);
        const f32x4 uv0 = __builtin_nontemporal_load(u4 + i);
        const f32x4 lv1 = __builtin_nontemporal_load(l4 + j);
        const f32x4 uv1 = __builtin_nontemporal_load(u4 + j);
        f32x4 a0, b0, a1, b1;
        spu_bounds4(lv0, uv0, a0, b0);
        spu_bounds4(lv1, uv1, a1, b1);
        __builtin_nontemporal_store(a0, nl4 + i);
        __builtin_nontemporal_store(b0, nu4 + i);
        __builtin_nontemporal_store(a1, nl4 + j);
        __builtin_nontemporal_store(b1, nu4 + j);
    }

    // odd leftover float4 (if n4 is odd)
    for (int i = 2 * pairs + tid; i < n4; i += stride) {
        const f32x4 lv = __builtin_nontemporal_load(l4 + i);
        const f32x4 uv = __builtin_nontemporal_load(u4 + i);
        f32x4 a, b;
        spu_bounds4(lv, uv, a, b);
        __builtin_nontemporal_store(a, nl4 + i);
        __builtin_nontemporal_store(b, nu4 + i);
    }

    // scalar tail (n % 4 != 0)
    for (int i = n4 * 4 + tid; i < n; i += stride) {
        spu_bounds(l[i], u[i], out_nl[i], out_nu[i]);
    }
}

extern "C" void kernel_launch(void* const* d_in, const int* in_sizes, int n_in,
                              void* d_out, int out_size, void* d_ws, size_t ws_size,
                              hipStream_t stream) {
    const float* l = (const float*)d_in[0];
    const float* u = (const float*)d_in[1];
    float* out = (float*)d_out;

    const int n = in_sizes[0];          // 64 * 65536 = 4194304
    float* out_nl = out;                // first output, flat
    float* out_nu = out + n;            // second output, flat

    const int n4 = n / 4;
    const int pairs = n4 / 2;
    const int block = 256;
    int grid = (pairs + block - 1) / block;   // 2048 for n=4194304
    if (grid > 4096) grid = 4096;             // grid-stride beyond this
    if (grid < 1) grid = 1;

    spu_pointwise_kernel<<<grid, block, 0, stream>>>(l, u, out_nl, out_nu, n4, n);
}

// Round 6
// 15.570 us; speedup vs baseline: 1.1432x; 1.1432x over previous
//
#include <hip/hip_runtime.h>
#include <math.h>

typedef float f32x4 __attribute__((ext_vector_type(4)));

__device__ __forceinline__ float frcp(float x) { return __builtin_amdgcn_rcpf(x); }

// SPU(x) = x^2 - 0.5 (x>=0), 1/(1+e^x) - 1 (x<0); grad = 2x (x>=0), -e^x/(1+e^x)^2 (x<0).
// Branchless union-path evaluation, instruction-minimized.
__device__ __forceinline__ void spu_bounds(float l, float u, float& nl, float& nu) {
    const float mid = 0.5f * (l + u);
    const float dlu = u - l;                 // >= 0 by construction

    const float e_l = __expf(l);
    const float e_u = __expf(u);
    const float e_m = __expf(mid);
    const float r_l = frcp(1.0f + e_l);
    const float r_u = frcp(1.0f + e_u);
    const float r_m = frcp(1.0f + e_m);
    const float rg  = frcp(dlu + 1e-8f);     // chord guard
    const float rl0 = frcp(1e-8f - l);       // l->0 chord guard

    const float sl = (l   >= 0.0f) ? fmaf(l,   l,   -0.5f) : (r_l - 1.0f);
    const float su = (u   >= 0.0f) ? fmaf(u,   u,   -0.5f) : (r_u - 1.0f);
    const float sm = (mid >= 0.0f) ? fmaf(mid, mid, -0.5f) : (r_m - 1.0f);
    // grad at mid; for mid < -50, e_m underflows so gm ~ -2e-22 ~ 0 (ref clamps to 0; diff negligible)
    const float gm = (mid >= 0.0f) ? (mid + mid) : (-e_m * r_m * r_m);

    const float a_lu = (su - sl) * rg;             // chord slope
    const float b_lu = fmaf(-l, a_lu, sl);
    const float b_t  = fmaf(-gm, mid, sm);         // tangent intercept

    const bool neg    = (u < 0.0f);
    const bool pos    = (!neg) && (l > 0.0f);
    const bool normal = (!neg) && (!pos) && (su > sl);

    // mixed-case lower-bound candidates
    const float a1 = (-0.5f - sl) * rl0;           // chord l -> 0
    const float b1 = fmaf(-l, a1, sl);
    const float b2 = -fmaf(0.25f * u, u, 0.5f);    // tangent at u/2: a2 = u

    // area proxy ar_i = -dlu * x_i; argmin(ar) == first strict-max of x (dlu>=0).
    // x0 = -1 (a=0,b=-0.5); x1 = a1*dlu + 2*sl; x2 = u^2/2 + u*l - 1.
    // (dlu==0 corner: mixed => l=u=0 => x1 tie gives identical (0,-0.5)).
    const float x1 = fmaf(a1, dlu, sl + sl);
    const float x2 = fmaf(u, fmaf(0.5f, u, l), -1.0f);

    const bool  c1 = (x1 > -1.0f);
    float am = c1 ? a1 : 0.0f;
    float bm = c1 ? b1 : -0.5f;
    const float xb = c1 ? x1 : -1.0f;
    const bool  c2 = normal && (x2 > xb);
    am = c2 ? u  : am;
    bm = c2 ? b2 : bm;

    const float lw = neg ? a_lu : (pos ? gm  : am);
    const float lb = neg ? b_lu : (pos ? b_t : bm);
    const bool  uc = (!neg) && (pos || normal);    // upper bound uses chord
    const float uw = neg ? gm  : (uc ? a_lu : 0.0f);
    const float ub = neg ? b_t : (uc ? b_lu : sl);

    // l <= u:  where(lw>0, lw*l, lw*u) == min;  where(uw>0, uw*u, uw*l) == max
    nl = lb + fminf(lw * l, lw * u);
    nu = ub + fmaxf(uw * l, uw * u);
}

__global__ void __launch_bounds__(256) spu_pointwise_kernel(
        const float* __restrict__ l, const float* __restrict__ u,
        float* __restrict__ out_nl, float* __restrict__ out_nu,
        int n4, int n) {
    const int tid = blockIdx.x * blockDim.x + threadIdx.x;
    const int stride = gridDim.x * blockDim.x;

    const f32x4* __restrict__ l4 = reinterpret_cast<const f32x4*>(l);
    const f32x4* __restrict__ u4 = reinterpret_cast<const f32x4*>(u);
    f32x4* __restrict__ nl4 = reinterpret_cast<f32x4*>(out_nl);
    f32x4* __restrict__ nu4 = reinterpret_cast<f32x4*>(out_nu);

    for (int i = tid; i < n4; i += stride) {
        const f32x4 lv = l4[i];            // plain loads: inputs are L3-resident
        const f32x4 uv = u4[i];
        float a0, b0, a1, b1, a2, b2, a3, b3;
        spu_bounds(lv.x, uv.x, a0, b0);
        spu_bounds(lv.y, uv.y, a1, b1);
        spu_bounds(lv.z, uv.z, a2, b2);
        spu_bounds(lv.w, uv.w, a3, b3);
        f32x4 a, b;
        a.x = a0; a.y = a1; a.z = a2; a.w = a3;
        b.x = b0; b.y = b1; b.z = b2; b.w = b3;
        __builtin_nontemporal_store(a, nl4 + i);   // streaming outputs
        __builtin_nontemporal_store(b, nu4 + i);
    }

    // scalar tail (n % 4 != 0)
    for (int i = n4 * 4 + tid; i < n; i += stride) {
        spu_bounds(l[i], u[i], out_nl[i], out_nu[i]);
    }
}

extern "C" void kernel_launch(void* const* d_in, const int* in_sizes, int n_in,
                              void* d_out, int out_size, void* d_ws, size_t ws_size,
                              hipStream_t stream) {
    const float* l = (const float*)d_in[0];
    const float* u = (const float*)d_in[1];
    float* out = (float*)d_out;

    const int n = in_sizes[0];          // 64 * 65536 = 4194304
    float* out_nl = out;                // first output, flat
    float* out_nu = out + n;            // second output, flat

    const int n4 = n / 4;
    const int block = 256;
    int grid = (n4 + block - 1) / block;
    if (grid > 4096) grid = 4096;       // grid-stride beyond this
    if (grid < 1) grid = 1;

    spu_pointwise_kernel<<<grid, block, 0, stream>>>(l, u, out_nl, out_nu, n4, n);
}

// Round 7
// 15.489 us; speedup vs baseline: 1.1491x; 1.0052x over previous
//
#include <hip/hip_runtime.h>
#include <math.h>

typedef float f32x4 __attribute__((ext_vector_type(4)));

__device__ __forceinline__ float frcp(float x) { return __builtin_amdgcn_rcpf(x); }

// SPU(x) = x^2 - 0.5 (x>=0), 1/(1+e^x) - 1 (x<0); grad = 2x (x>=0), -e^x/(1+e^x)^2 (x<0).
// Case-resolved corner evaluation:
//   neg   (u<0):          nl = chord@u  = su (guard err ~4e-7), nu = tangent@l = TL
//   pos   (l>0):          nl = TL,                              nu = chord@u  = su
//   mixed normal (su>sl): nl = argmin-area line @ its corner,   nu = su
//   mixed small:          nl = same,                            nu = sl
__device__ __forceinline__ void spu_bounds(float l, float u, float& nl, float& nu) {
    const float mid = 0.5f * (l + u);
    const float dlu = u - l;                    // >= 0

    const float e_l = __expf(l);
    const float e_u = __expf(u);
    const float e_m = __expf(mid);
    const float r_l = frcp(1.0f + e_l);
    const float r_u = frcp(1.0f + e_u);
    const float r_m = frcp(1.0f + e_m);
    const float rl0 = frcp(1e-8f - l);          // chord l->0 guard

    const bool mpos = (mid >= 0.0f);
    const float sl = (l >= 0.0f) ? fmaf(l, l, -0.5f) : (r_l - 1.0f);
    const float su = (u >= 0.0f) ? fmaf(u, u, -0.5f) : (r_u - 1.0f);
    const float sm = mpos ? fmaf(mid, mid, -0.5f) : (r_m - 1.0f);
    // gmh = -0.5 * spu_grad(mid); for mid <= -87 e_m underflows to 0 -> gmh = 0 (matches ref clamp)
    const float gmh = mpos ? (-mid) : (0.5f * e_m * r_m * r_m);

    const float TL = fmaf(gmh, dlu, sm);        // tangent at mid, evaluated at l

    const bool neg    = (u < 0.0f);
    const bool pos    = (!neg) && (l > 0.0f);
    const bool normal = (!neg) && (!pos) && (su > sl);

    // mixed lower-bound candidates, each evaluated at its active corner:
    const float a1 = (-0.5f - sl) * rl0;        // chord l->0 slope (<= 0)
    const float n1 = fmaf(a1, dlu, sl);         // chord(l->0) @ u
    const float p  = fmaf(0.25f * u, u, 0.5f);
    const float n2 = fmaf(u, l, -p);            // tangent@u/2 (slope u>=0) @ l

    // area argmin via y_i = a_i*(l+u) + 2*b_i  (ar_i = -dlu*y_i; first strict-max of y)
    const float x1 = n1 + sl;                   // = a1*dlu + 2*sl
    const float x2 = fmaf(u, fmaf(0.5f, u, l), -1.0f);   // = u^2/2 + u*l - 1

    const bool  c1   = (x1 > -1.0f);
    const float nl01 = c1 ? n1 : -0.5f;
    const float xb   = c1 ? x1 : -1.0f;
    const bool  c2   = normal && (x2 > xb);
    const float nlm  = c2 ? n2 : nl01;

    nl = neg ? su : (pos ? TL : nlm);
    nu = neg ? TL : ((pos || normal) ? su : sl);
}

__global__ void __launch_bounds__(256) spu_pointwise_kernel(
        const float* __restrict__ l, const float* __restrict__ u,
        float* __restrict__ out_nl, float* __restrict__ out_nu,
        int n4, int n) {
    const int tid = blockIdx.x * blockDim.x + threadIdx.x;
    const int stride = gridDim.x * blockDim.x;

    const f32x4* __restrict__ l4 = reinterpret_cast<const f32x4*>(l);
    const f32x4* __restrict__ u4 = reinterpret_cast<const f32x4*>(u);
    f32x4* __restrict__ nl4 = reinterpret_cast<f32x4*>(out_nl);
    f32x4* __restrict__ nu4 = reinterpret_cast<f32x4*>(out_nu);

    for (int i = tid; i < n4; i += stride) {
        const f32x4 lv = l4[i];            // inputs are L2/L3-resident: plain loads
        const f32x4 uv = u4[i];
        float a0, b0, a1, b1, a2, b2, a3, b3;
        spu_bounds(lv.x, uv.x, a0, b0);
        spu_bounds(lv.y, uv.y, a1, b1);
        spu_bounds(lv.z, uv.z, a2, b2);
        spu_bounds(lv.w, uv.w, a3, b3);
        f32x4 a, b;
        a.x = a0; a.y = a1; a.z = a2; a.w = a3;
        b.x = b0; b.y = b1; b.z = b2; b.w = b3;
        __builtin_nontemporal_store(a, nl4 + i);   // streaming outputs
        __builtin_nontemporal_store(b, nu4 + i);
    }

    // scalar tail (n % 4 != 0)
    for (int i = n4 * 4 + tid; i < n; i += stride) {
        spu_bounds(l[i], u[i], out_nl[i], out_nu[i]);
    }
}

extern "C" void kernel_launch(void* const* d_in, const int* in_sizes, int n_in,
                              void* d_out, int out_size, void* d_ws, size_t ws_size,
                              hipStream_t stream) {
    const float* l = (const float*)d_in[0];
    const float* u = (const float*)d_in[1];
    float* out = (float*)d_out;

    const int n = in_sizes[0];          // 64 * 65536 = 4194304
    float* out_nl = out;                // first output, flat
    float* out_nu = out + n;            // second output, flat

    const int n4 = n / 4;
    const int block = 256;
    int grid = (n4 + block - 1) / block;    // 4096 for n=4194304: 1 float4/thread
    if (grid > 8192) grid = 8192;           // grid-stride beyond this
    if (grid < 1) grid = 1;

    spu_pointwise_kernel<<<grid, block, 0, stream>>>(l, u, out_nl, out_nu, n4, n);
}